// Round 6
// baseline (258.514 us; speedup 1.0000x reference)
//
#include <hip/hip_runtime.h>
#include <hip/hip_bf16.h>

typedef unsigned short ushort_t;
typedef __attribute__((ext_vector_type(8))) short short8;   // 8 x bf16 (4 VGPRs)
typedef __attribute__((ext_vector_type(4))) float floatx4;  // MFMA acc

#define BATCH 4
#define SEQ   2048
#define CH    1024
#define NHEAD 16
#define HSZ   64
#define MROWS (BATCH * SEQ)  // 8192

// async global->LDS, 16B per lane; LDS dest = wave-uniform base + lane*16
#define GLD16(gptr, lptr) \
    __builtin_amdgcn_global_load_lds((const __attribute__((address_space(1))) unsigned int*)(gptr), \
                                     (__attribute__((address_space(3))) unsigned int*)(lptr), 16, 0, 0)

__device__ inline ushort_t f2b(float f) {
    __hip_bfloat16 h = __float2bfloat16(f);
    return *(ushort_t*)&h;
}
__device__ inline float b2f(ushort_t u) {
    return __bfloat162float(*(__hip_bfloat16*)&u);
}

// raw v_exp_f32: OCML exp2f adds a denormal-range guard (~5 VALU insts/call)
// we don't need — masked inputs are -1e30 and raw v_exp_f32(-1e30) = +0.
__device__ __forceinline__ float fast_exp2(float x) {
#if __has_builtin(__builtin_amdgcn_exp2f)
    return __builtin_amdgcn_exp2f(x);
#else
    float r; asm("v_exp_f32 %0, %1" : "=v"(r) : "v"(x)); return r;
#endif
}

// -------- dtype detect (parallel): *flag = 1 if x is bf16, 0 if f32 --------------
__global__ void detect_dtype(const ushort_t* __restrict__ x, int* __restrict__ flag) {
    int cnt = 0;
    #pragma unroll
    for (int i = 0; i < 8; i++) {
        const int e = (x[2 * (threadIdx.x * 8 + i)] >> 7) & 0xFF;
        const unsigned long long m = __ballot(e >= 100 && e <= 140);
        cnt += (int)__popcll(m);
    }
    if (threadIdx.x == 0) *flag = (cnt >= 400) ? 1 : 0;
}

// -------- 4x weight transpose+convert: in[k][n] -> out bf16 [n][k] ---------------
__global__ __launch_bounds__(256) void convert_wt4(const void* w0, const void* w1,
                                                   const void* w2, const void* w3,
                                                   ushort_t* o0, ushort_t* o1,
                                                   ushort_t* o2, ushort_t* o3,
                                                   const int* __restrict__ flag) {
    __shared__ ushort_t tile[32][33];
    const void* in = (blockIdx.z == 0) ? w0 : (blockIdx.z == 1) ? w1 : (blockIdx.z == 2) ? w2 : w3;
    ushort_t*  out = (blockIdx.z == 0) ? o0 : (blockIdx.z == 1) ? o1 : (blockIdx.z == 2) ? o2 : o3;
    const int am = *flag;
    const int bx = blockIdx.x * 32, by = blockIdx.y * 32;
    const int tx = threadIdx.x & 31, ty = threadIdx.x >> 5;
    #pragma unroll
    for (int r = ty; r < 32; r += 8) {
        const size_t idx = (size_t)(by + r) * CH + bx + tx;
        tile[r][tx] = am ? ((const ushort_t*)in)[idx] : f2b(((const float*)in)[idx]);
    }
    __syncthreads();
    #pragma unroll
    for (int r = ty; r < 32; r += 8)
        out[(size_t)(bx + r) * CH + by + tx] = tile[tx][r];
}

// -------- 4x bias convert --------------------------------------------------------
__global__ void convert_bias4(const void* b0, const void* b1, const void* b2, const void* b3,
                              ushort_t* __restrict__ out, const int* __restrict__ flag) {
    const int i = blockIdx.x * 256 + threadIdx.x;  // 0..4095
    const int m = i >> 10, idx = i & 1023;
    const void* in = (m == 0) ? b0 : (m == 1) ? b1 : (m == 2) ? b2 : b3;
    out[i] = (*flag) ? ((const ushort_t*)in)[idx] : f2b(((const float*)in)[idx]);
}

// -------- x convert: flat fp32/bf16 -> bf16, 8 elems/thread ----------------------
__global__ __launch_bounds__(256) void convert_x(const void* __restrict__ in,
                                                 ushort_t* __restrict__ out,
                                                 const int* __restrict__ flag) {
    const int i = (blockIdx.x * 256 + threadIdx.x) * 8;
    if (*flag) {
        *(float4*)&out[i] = *(const float4*)&((const ushort_t*)in)[i];
    } else {
        const float* p = (const float*)in + i;
        float4 f0 = *(const float4*)p;
        float4 f1 = *(const float4*)(p + 4);
        ushort_t t[8] = {f2b(f0.x), f2b(f0.y), f2b(f0.z), f2b(f0.w),
                         f2b(f1.x), f2b(f1.y), f2b(f1.z), f2b(f1.w)};
        *(float4*)&out[i] = *(const float4*)t;
    }
}

// ========= 256^2 / BK=32 / 3-buf / wave-tile 128x64 QKV GEMM (R5 post-mortem) ====
// R3/R4/R5 all plateaued at ~718 TF with 64x64 wave tiles = 0.5 ds_read_b128 per
// MFMA -> 1.6 GB LDS reads -> ~31 us LDS-port floor. m201's wave tile 128x64
// (acc[8][4]) cuts reads to 0.375/MFMA and is the proven 1563-TF geometry.
// BK=32 instead of 64 so THREE buffers fit LDS (3 x (16K A + 16K B) = 96 KB),
// giving a genuinely counted vmcnt(4) tile gate (t+2's 4 loads in flight; t+1's
// 4 are a full tile old) — no vmcnt(0) drain in the main loop (m218).
// Per K-tile: 2 phases x {ds_read (8 or 4 b128, PRE-barrier) -> 2 GLD16 ->
// barrier -> setprio(1) 16 MFMA setprio(0) -> [gate] -> barrier}.
// Swizzle (rule 21, both sides): logical unit u (8 elems) of row r stored at
// phys u^((r>>1)&3); stage keeps LINEAR dest (base+tid*16B) by pre-swizzling the
// global source unit (tid&3)^((tid>>3)&3); reads use phys = quad^((lane15>>1)&3)
// -> 2 lanes/bank (free, m136). K-accumulation stays k-ascending: bitwise-same.
// Buffer rotation: tile t reads buf t%3; stages during t write buf (t+2)%3; the
// last reader of that buf was tile t-1, already past its MFMA lgkm-wait and the
// t-1 end barrier before any tile-t stage issues (same proof as R5, which passed).
__global__ __launch_bounds__(512) void gemm_qkv9(const ushort_t* __restrict__ A,
                                                 const ushort_t* __restrict__ Bt,
                                                 const ushort_t* __restrict__ bias,
                                                 ushort_t* __restrict__ Qb,
                                                 ushort_t* __restrict__ Kb,
                                                 ushort_t* __restrict__ Vt,
                                                 float qscale) {
    __shared__ __align__(16) ushort_t As[3][256 * 32];   // 3 x 16 KB
    __shared__ __align__(16) ushort_t Bs[3][256 * 32];   // 3 x 16 KB
    const int tid = threadIdx.x;
    const int lane = tid & 63, wave = tid >> 6;
    const int lane15 = lane & 15, quad = lane >> 4;
    const int wm = wave >> 2, wn = wave & 3;             // 2M x 4N wave grid
    const int k15 = (lane15 >> 1) & 3;                   // read-side swizzle key
    const int srow = tid >> 2;                           // staging row 0..127
    const int sulog = (tid & 3) ^ ((tid >> 3) & 3);      // pre-swizzled source unit
    // XCD-chunked bijective swizzle: grid 384 (32 rowblk x 12 colblk), cpx=48
    const int bid = blockIdx.x;
    const int bidl = (bid & 7) * 48 + (bid >> 3);
    const int rowblk = bidl / 12, colblk = bidl - rowblk * 12;
    const int row0 = rowblk * 256, col0 = colblk * 256;
    const int seg = col0 >> 10;                          // 0=Q 1=K 2=V (uniform)

    floatx4 acc[8][4];
    #pragma unroll
    for (int m = 0; m < 8; m++)
        #pragma unroll
        for (int n = 0; n < 4; n++) acc[m][n] = {0.f, 0.f, 0.f, 0.f};

    // stage half h (rows h*128..h*128+127) of K-tile tt: 1 A + 1 B load/thread
    auto stage_h = [&](int bf, int tt, int h) {
        const int kof = tt * 32 + sulog * 8;
        const int r = h * 128 + srow;
        GLD16(A  + (size_t)(row0 + r) * CH + kof, &As[bf][r * 32 + (tid & 3) * 8]);
        GLD16(Bt + (size_t)(col0 + r) * CH + kof, &Bs[bf][r * 32 + (tid & 3) * 8]);
    };

    // prologue: stage tiles 0 and 1 (4 loads each)
    stage_h(0, 0, 0); stage_h(0, 0, 1);
    stage_h(1, 1, 0); stage_h(1, 1, 1);
    asm volatile("s_waitcnt vmcnt(4)" ::: "memory");     // tile 0's 4 landed
    __builtin_amdgcn_s_barrier();

    int buf = 0;
    for (int t = 0; t < 32; ++t) {
        const ushort_t* Ab = As[buf];
        const ushort_t* Bb = Bs[buf];
        int bnext = buf + 2; if (bnext >= 3) bnext -= 3;
        const bool pf = (t + 2 < 32);
        short8 af[4], bfr[4];
        // ---- phase 0: m 0..3, all b-frags
        #pragma unroll
        for (int m = 0; m < 4; m++)
            af[m] = *(const short8*)&Ab[(wm * 128 + m * 16 + lane15) * 32 + ((quad ^ k15) * 8)];
        #pragma unroll
        for (int n = 0; n < 4; n++)
            bfr[n] = *(const short8*)&Bb[(wn * 64 + n * 16 + lane15) * 32 + ((quad ^ k15) * 8)];
        if (pf) stage_h(bnext, t + 2, 0);
        __builtin_amdgcn_s_barrier();
        __builtin_amdgcn_s_setprio(1);
        #pragma unroll
        for (int m = 0; m < 4; m++)
            #pragma unroll
            for (int n = 0; n < 4; n++)
                acc[m][n] = __builtin_amdgcn_mfma_f32_16x16x32_bf16(af[m], bfr[n], acc[m][n], 0, 0, 0);
        __builtin_amdgcn_s_setprio(0);
        __builtin_amdgcn_s_barrier();
        // ---- phase 1: m 4..7 (b-frags reused from phase 0)
        #pragma unroll
        for (int m = 0; m < 4; m++)
            af[m] = *(const short8*)&Ab[(wm * 128 + (m + 4) * 16 + lane15) * 32 + ((quad ^ k15) * 8)];
        if (pf) stage_h(bnext, t + 2, 1);
        __builtin_amdgcn_s_barrier();
        __builtin_amdgcn_s_setprio(1);
        #pragma unroll
        for (int m = 0; m < 4; m++)
            #pragma unroll
            for (int n = 0; n < 4; n++)
                acc[m + 4][n] = __builtin_amdgcn_mfma_f32_16x16x32_bf16(af[m], bfr[n], acc[m + 4][n], 0, 0, 0);
        __builtin_amdgcn_s_setprio(0);
        if (t < 31) {
            // gate tile t+1's reads: its 4 loads are the oldest outstanding
            if (pf) asm volatile("s_waitcnt vmcnt(4)" ::: "memory");
            else    asm volatile("s_waitcnt vmcnt(0)" ::: "memory");  // t=30 drain (old loads)
        }
        __builtin_amdgcn_s_barrier();
        buf = (buf == 2) ? 0 : buf + 1;
    }

    // epilogue: per-segment stores, wave tile 128x64
    #pragma unroll
    for (int n = 0; n < 4; n++) {
        const int col = col0 + wn * 64 + n * 16 + lane15;
        const float bv = b2f(bias[col]);
        #pragma unroll
        for (int m = 0; m < 8; m++) {
            const int rowb = row0 + wm * 128 + m * 16 + quad * 4;
            if (seg == 0) {
                #pragma unroll
                for (int r = 0; r < 4; r++)
                    Qb[(size_t)(rowb + r) * CH + col] = f2b((acc[m][n][r] + bv) * qscale);
            } else if (seg == 1) {
                const int c = col - 1024;
                #pragma unroll
                for (int r = 0; r < 4; r++)
                    Kb[(size_t)(rowb + r) * CH + c] = f2b(acc[m][n][r] + bv);
            } else {
                const int c = col - 2048;
                ushort_t pk[4];
                #pragma unroll
                for (int r = 0; r < 4; r++) pk[r] = f2b(acc[m][n][r] + bv);
                const int bb = rowb >> 11, tc = rowb & 2047;
                *(uint2*)&Vt[((size_t)bb * 1024 + c) * 2048 + tc] = *(const uint2*)pk;
            }
        }
    }
}

// ======== 256x128 triple-buffered phase pipeline (R5, kept for gemm_bt) ==========
__device__ __forceinline__ void pipe256x128(const ushort_t* __restrict__ A,
                                            const ushort_t* __restrict__ Bt,
                                            int row0, int col0,
                                            ushort_t* __restrict__ As,   // [3][256*64]
                                            ushort_t* __restrict__ Bs,   // [3][128*64]
                                            floatx4 acc[4][4], int tid) {
    const int lane = tid & 63, wave = tid >> 6;
    const int lane15 = lane & 15, quad = lane >> 4;
    const int s7 = lane15 & 7;                       // read-side swizzle key
    const int wm = wave >> 1, wn = wave & 1;         // 4M x 2N wave grid
    const int lrow = lane >> 3, lu = lane & 7, gu = lu ^ lrow;          // A staging
    const int brow = tid >> 3, bu = tid & 7, bgu = bu ^ (brow & 7);     // B staging

    auto stage_part = [&](int buf, int tt, int h) {
        ushort_t* Ad = As + buf * (256 * 64) + (h * 128 + wave * 16 + lrow) * 64 + lu * 8;
        const ushort_t* Asrc = A + (size_t)(row0 + h * 128 + wave * 16 + lrow) * CH + tt * 64 + gu * 8;
        GLD16(Asrc, Ad);
        GLD16(Asrc + 8 * CH, Ad + 8 * 64);           // row+8: same &7 -> same gu
        ushort_t* Bd = Bs + buf * (128 * 64) + (h * 64 + brow) * 64 + bu * 8;
        const ushort_t* Bsrc = Bt + (size_t)(col0 + h * 64 + brow) * CH + tt * 64 + bgu * 8;
        GLD16(Bsrc, Bd);
    };

    stage_part(0, 0, 0); stage_part(0, 0, 1);
    stage_part(1, 1, 0); stage_part(1, 1, 1);
    asm volatile("s_waitcnt vmcnt(6)" ::: "memory");  // tile 0's 6 landed
    __builtin_amdgcn_s_barrier();

    int buf = 0;
    for (int t = 0; t < 16; ++t) {
        const ushort_t* Ab = As + buf * (256 * 64) + (wm * 64) * 64;
        const ushort_t* Bb = Bs + buf * (128 * 64) + (wn * 64) * 64;
        int bnext = buf + 2; if (bnext >= 3) bnext -= 3;
        const bool pf = (t + 2 < 16);
        #pragma unroll
        for (int kk = 0; kk < 2; ++kk) {
            short8 af[4], bfr[4];
            #pragma unroll
            for (int i = 0; i < 4; i++)
                af[i] = *(const short8*)&Ab[(i * 16 + lane15) * 64 + (((kk * 4 + quad) ^ s7) * 8)];
            #pragma unroll
            for (int j = 0; j < 4; j++)
                bfr[j] = *(const short8*)&Bb[(j * 16 + lane15) * 64 + (((kk * 4 + quad) ^ s7) * 8)];
            if (pf) stage_part(bnext, t + 2, kk);
            __builtin_amdgcn_s_barrier();
            __builtin_amdgcn_s_setprio(1);
            #pragma unroll
            for (int i = 0; i < 4; i++)
                #pragma unroll
                for (int j = 0; j < 4; j++)
                    acc[i][j] = __builtin_amdgcn_mfma_f32_16x16x32_bf16(af[i], bfr[j], acc[i][j], 0, 0, 0);
            __builtin_amdgcn_s_setprio(0);
            if (kk == 1 && t < 15) {
                if (pf) asm volatile("s_waitcnt vmcnt(6)" ::: "memory");
                else    asm volatile("s_waitcnt vmcnt(0)" ::: "memory");  // t=14 drain
            }
            __builtin_amdgcn_s_barrier();
        }
        buf = (buf == 2) ? 0 : buf + 1;
    }
}

// ---------------- output GEMM: Out[8192,1024] = A @ WoT^T + bias -----------------
__global__ __launch_bounds__(512) void gemm_bt8(const ushort_t* __restrict__ A,
                                                const ushort_t* __restrict__ Bt,
                                                const ushort_t* __restrict__ bias,
                                                void* __restrict__ Out,
                                                const int* __restrict__ oflag) {
    __shared__ __align__(16) ushort_t As[3 * 256 * 64];   // 96 KB
    __shared__ __align__(16) ushort_t Bs[3 * 128 * 64];   // 48 KB
    const int om = *oflag;
    const int tid = threadIdx.x;
    const int lane = tid & 63, wave = tid >> 6;
    const int lane15 = lane & 15, quad = lane >> 4;
    const int wm = wave >> 1, wn = wave & 1;
    // grid 256 = exactly 1 round; cpx = 32
    const int bid = blockIdx.x;
    const int bidl = (bid & 7) * 32 + (bid >> 3);
    const int rowblk = bidl >> 3, colblk = bidl & 7;
    const int row0 = rowblk * 256, col0 = colblk * 128;

    floatx4 acc[4][4];
    #pragma unroll
    for (int i = 0; i < 4; i++)
        #pragma unroll
        for (int j = 0; j < 4; j++) acc[i][j] = {0.f, 0.f, 0.f, 0.f};

    pipe256x128(A, Bt, row0, col0, As, Bs, acc, tid);

    #pragma unroll
    for (int j = 0; j < 4; j++) {
        const int col = col0 + wn * 64 + j * 16 + lane15;
        const float bv = b2f(bias[col]);
        #pragma unroll
        for (int i = 0; i < 4; i++) {
            const int rowb = row0 + wm * 64 + i * 16 + quad * 4;
            #pragma unroll
            for (int r = 0; r < 4; r++) {
                const float val = acc[i][j][r] + bv;
                const size_t idx = (size_t)(rowb + r) * CH + col;
                if (om) ((ushort_t*)Out)[idx] = f2b(val);
                else    ((float*)Out)[idx] = val;
            }
        }
    }
}

// ---------------- flash attention (round-6 structure + S^T write path) -----------
// Keep: K/V dbuf, one barrier per tile, XCD-local (b,h) in bid&63, ones-MFMA
// rowsum, exp2 with scale folded into Q, swizzled K/V staging, Ps LDS round
// trip (decouples S from PV across waves). DO NOT add a second
// __launch_bounds__ arg (round-7 spill).
// R1 (kept): fast_exp2 raw v_exp_f32; Ps stride-64 4-bit XOR chunk swizzle
// (b64 writes and split-b64 PV reads both bank-conflict-free).
__global__ __launch_bounds__(256) void attn_fwd(ushort_t* __restrict__ QY,
                                                const ushort_t* __restrict__ K,
                                                const ushort_t* __restrict__ Vt) {
    __shared__ __align__(16) ushort_t Ks[2][64 * 64];    // [buf][kv][d], swizzled
    __shared__ __align__(16) ushort_t Vs[2][64 * 64];    // [buf][d][kv], swizzled
    __shared__ __align__(16) ushort_t Ps[4 * 32 * 64];   // per-wave [q=32][kv=64], XOR-swizzled
    const int tid = threadIdx.x;
    const int lane = tid & 63, wave = tid >> 6;
    const int lane15 = lane & 15, quad = lane >> 4;
    const int sw = lane15 & 7;                            // read-side swizzle key
    const int bid = blockIdx.x;
    const int hb = bid & 63, qslot = bid >> 6;
    const int qb = 15 - qslot;
    const int h = hb & 15, b = hb >> 4;
    const int q0 = qb * 128;
    const size_t baseR = (size_t)b * SEQ * CH + h * HSZ;      // +t*CH+d (Q,K,Y)
    const size_t baseV = ((size_t)b * 1024 + h * HSZ) * SEQ;  // +d*SEQ+t (Vt)
    const int rg = lane >> 3, cg = (lane & 7) ^ rg;           // staging swizzle
    const int psBase = wave * 2048;                           // per-wave Ps region

    short8 qf[2][2];
    #pragma unroll
    for (int mm = 0; mm < 2; mm++) {
        const ushort_t* qp = QY + baseR + (size_t)(q0 + wave * 32 + mm * 16 + lane15) * CH + quad * 8;
        qf[mm][0] = *(const short8*)qp;
        qf[mm][1] = *(const short8*)(qp + 32);
    }
    const short8 kOnes = (short8)(short)0x3F80;  // bf16 1.0 x8

    floatx4 o[2][5];  // [mm][0..3]=O d-chunks, [4]=l (rowsum)
    #pragma unroll
    for (int mm = 0; mm < 2; mm++)
        #pragma unroll
        for (int j = 0; j < 5; j++) o[mm][j] = {0.f, 0.f, 0.f, 0.f};

    const int nkt = 2 * qb + 2;
    // preamble: stage tile 0 into buf 0
    #pragma unroll
    for (int l = wave; l < 8; l += 4) {
        GLD16(K  + baseR + (size_t)(l * 8 + rg) * CH + cg * 8, &Ks[0][l * 512]);
        GLD16(Vt + baseV + (size_t)(l * 8 + rg) * SEQ + cg * 8, &Vs[0][l * 512]);
    }

    for (int kt = 0; kt < nkt; kt++) {
        __syncthreads();  // staging of kt landed; all waves done with buf kt^1
        const int cur = kt & 1;
        if (kt + 1 < nkt) {
            const int kv1 = (kt + 1) * 64, nb = cur ^ 1;
            #pragma unroll
            for (int l = wave; l < 8; l += 4) {
                GLD16(K  + baseR + (size_t)(kv1 + l * 8 + rg) * CH + cg * 8, &Ks[nb][l * 512]);
                GLD16(Vt + baseV + (size_t)(l * 8 + rg) * SEQ + kv1 + cg * 8, &Vs[nb][l * 512]);
            }
        }
        const int kv0 = kt * 64;
        const int masked = (kt >= 2 * qb);

        // K fragments shared by both q-groups: a-frag of S^T = K[kv][d]
        short8 kf[4][2];
        #pragma unroll
        for (int g = 0; g < 4; g++) {
            kf[g][0] = *(const short8*)&Ks[cur][(g * 16 + lane15) * 64 + ((quad ^ sw) * 8)];
            kf[g][1] = *(const short8*)&Ks[cur][(g * 16 + lane15) * 64 + (((quad + 4) ^ sw) * 8)];
        }

        #pragma unroll
        for (int mm = 0; mm < 2; mm++) {
            const int qrow = q0 + wave * 32 + mm * 16 + lane15;
            const int rowOff = psBase + (mm * 16 + lane15) * 64;
            #pragma unroll
            for (int g = 0; g < 4; g++) {
                // z = S^T[kv = kv0+g*16+quad*4+r][q = qrow]
                floatx4 z = {0.f, 0.f, 0.f, 0.f};
                z = __builtin_amdgcn_mfma_f32_16x16x32_bf16(kf[g][0], qf[mm][0], z, 0, 0, 0);
                z = __builtin_amdgcn_mfma_f32_16x16x32_bf16(kf[g][1], qf[mm][1], z, 0, 0, 0);
                if (masked) {
                    #pragma unroll
                    for (int r = 0; r < 4; r++) {
                        const int col = kv0 + g * 16 + quad * 4 + r;
                        z[r] = (col <= qrow) ? z[r] : -1e30f;
                    }
                }
                // p = 2^z (raw v_exp_f32: 2^-1e30 -> 0 for masked lanes)
                const float p0 = fast_exp2(z[0]), p1 = fast_exp2(z[1]);
                const float p2 = fast_exp2(z[2]), p3 = fast_exp2(z[3]);
                unsigned int lo, hi;
                asm("v_cvt_pk_bf16_f32 %0, %1, %2" : "=v"(lo) : "v"(p0), "v"(p1));
                asm("v_cvt_pk_bf16_f32 %0, %1, %2" : "=v"(hi) : "v"(p2), "v"(p3));
                uint2 w; w.x = lo; w.y = hi;
                // logical 8B-chunk c = g*4+quad; physical = c ^ (row&15)
                *(uint2*)&Ps[rowOff + (((g * 4 + quad) ^ lane15) * 4)] = w;
            }
        }
        // Ps wave-private: lgkmcnt auto-wait orders write->read, no barrier

        #pragma unroll
        for (int kk = 0; kk < 2; kk++) {
            #pragma unroll
            for (int mm = 0; mm < 2; mm++) {
                // A-frag: logical chunks c0 = kk*8+quad*2, c0+1; swizzled apart
                const int rowOff = psBase + (mm * 16 + lane15) * 64;
                const int c0 = kk * 8 + quad * 2;
                short8 a;
                ((uint2*)&a)[0] = *(const uint2*)&Ps[rowOff + (((c0    ) ^ lane15) * 4)];
                ((uint2*)&a)[1] = *(const uint2*)&Ps[rowOff + (((c0 + 1) ^ lane15) * 4)];
                #pragma unroll
                for (int jn = 0; jn < 4; jn++) {
                    short8 bb = *(const short8*)&Vs[cur][(jn * 16 + lane15) * 64 + (((kk * 4 + quad) ^ sw) * 8)];
                    o[mm][jn] = __builtin_amdgcn_mfma_f32_16x16x32_bf16(a, bb, o[mm][jn], 0, 0, 0);
                }
                o[mm][4] = __builtin_amdgcn_mfma_f32_16x16x32_bf16(a, kOnes, o[mm][4], 0, 0, 0);
            }
        }
    }

    // epilogue: Y = O / l
    #pragma unroll
    for (int mm = 0; mm < 2; mm++)
        #pragma unroll
        for (int r = 0; r < 4; r++) {
            const int qrow = q0 + wave * 32 + mm * 16 + quad * 4 + r;
            const float rinv = 1.0f / fmaxf(o[mm][4][r], 1e-30f);
            #pragma unroll
            for (int jn = 0; jn < 4; jn++)
                QY[baseR + (size_t)qrow * CH + jn * 16 + lane15] = f2b(o[mm][jn][r] * rinv);
        }
}

extern "C" void kernel_launch(void* const* d_in, const int* in_sizes, int n_in,
                              void* d_out, int out_size, void* d_ws, size_t ws_size,
                              hipStream_t stream) {
    const void* x  = d_in[0];
    const void* Wk = d_in[1];
    const void* bk = d_in[2];
    const void* Wq = d_in[3];
    const void* bq = d_in[4];
    const void* Wv = d_in[5];
    const void* bv = d_in[6];
    const void* Wo = d_in[7];
    const void* bo = d_in[8];

    ushort_t* ws    = (ushort_t*)d_ws;
    int*      flag  = (int*)d_ws;
    ushort_t* biasC = ws + 2048;                    // 4x1024: q,k,v,o (contiguous)
    ushort_t* WqkvT = ws + 32768;                   // 3x1M contiguous: q,k,v
    ushort_t* WoT   = WqkvT + 3u * (1u << 20);
    ushort_t* xb    = ws + 4227072;                 // 8M elems bf16
    ushort_t* Qb    = ws + 12615680;                // 8M elems (becomes Y)
    ushort_t* Kb    = (ushort_t*)d_out;             // d_out scratch until final GEMM
    ushort_t* VtB   = Kb + (size_t)MROWS * CH;

    detect_dtype<<<1, 64, 0, stream>>>((const ushort_t*)x, flag);

    dim3 tgrid(32, 32, 4);
    convert_wt4<<<tgrid, 256, 0, stream>>>(Wq, Wk, Wv, Wo,
                                           WqkvT, WqkvT + (1u << 20), WqkvT + 2u * (1u << 20), WoT, flag);
    convert_bias4<<<16, 256, 0, stream>>>(bq, bk, bv, bo, biasC, flag);
    convert_x<<<MROWS * CH / (256 * 8), 256, 0, stream>>>(x, xb, flag);

    // scale = (1/sqrt(64)) * log2(e), folded into Q so attention uses exp2
    gemm_qkv9<<<dim3(384), 512, 0, stream>>>(xb, WqkvT, biasC, Qb, Kb, VtB, 0.1803368801f);

    attn_fwd<<<dim3(1024), 256, 0, stream>>>(Qb, Kb, VtB);

    gemm_bt8<<<dim3(256), 512, 0, stream>>>(Qb, WoT, biasC + 3072, d_out, flag);
}

// Round 7
// 249.791 us; speedup vs baseline: 1.0349x; 1.0349x over previous
//
#include <hip/hip_runtime.h>
#include <hip/hip_bf16.h>

typedef unsigned short ushort_t;
typedef __attribute__((ext_vector_type(8))) short short8;   // 8 x bf16 (4 VGPRs)
typedef __attribute__((ext_vector_type(4))) float floatx4;  // MFMA acc

#define BATCH 4
#define SEQ   2048
#define CH    1024
#define NHEAD 16
#define HSZ   64
#define MROWS (BATCH * SEQ)  // 8192

// async global->LDS, 16B per lane; LDS dest = wave-uniform base + lane*16
#define GLD16(gptr, lptr) \
    __builtin_amdgcn_global_load_lds((const __attribute__((address_space(1))) unsigned int*)(gptr), \
                                     (__attribute__((address_space(3))) unsigned int*)(lptr), 16, 0, 0)

__device__ inline ushort_t f2b(float f) {
    __hip_bfloat16 h = __float2bfloat16(f);
    return *(ushort_t*)&h;
}
__device__ inline float b2f(ushort_t u) {
    return __bfloat162float(*(__hip_bfloat16*)&u);
}

// raw v_exp_f32: OCML exp2f adds a denormal-range guard (~5 VALU insts/call)
// we don't need — masked inputs are -1e30 and raw v_exp_f32(-1e30) = +0.
__device__ __forceinline__ float fast_exp2(float x) {
#if __has_builtin(__builtin_amdgcn_exp2f)
    return __builtin_amdgcn_exp2f(x);
#else
    float r; asm("v_exp_f32 %0, %1" : "=v"(r) : "v"(x)); return r;
#endif
}

// ======== fused prep: dtype detect + weight transpose + bias + x convert =========
// R6 post-mortem: 4 separate kernels (1-block detect serializing 3 converts) cost
// ~3 extra launches + a dependency stall. One kernel, block-uniform branch:
//   blocks [0,4096):   4x weight transpose+convert (z = bid>>10)
//   blocks [4096,4112): bias convert (writes *flagOut from block 4096)
//   blocks [4112,8208): x convert, 8 elems/thread
// Per-block dtype self-detect from x's first 512 B: if x is bf16, x[2i] is a
// bf16 of N(0,1) -> exponent in [100,140] ~always; if f32, x[2i] is a mantissa
// low-half -> ~16% in range. 256 samples, threshold 128: error prob < 1e-8.
__global__ __launch_bounds__(256) void prep_all(const void* __restrict__ x,
        const void* __restrict__ w0, const void* __restrict__ w1,
        const void* __restrict__ w2, const void* __restrict__ w3,
        const void* __restrict__ b0, const void* __restrict__ b1,
        const void* __restrict__ b2, const void* __restrict__ b3,
        ushort_t* __restrict__ WqkvT, ushort_t* __restrict__ WoT,
        ushort_t* __restrict__ biasC, ushort_t* __restrict__ xb,
        int* __restrict__ flagOut) {
    __shared__ int cnts[4];
    __shared__ ushort_t tile[32][33];
    const int tid = threadIdx.x;
    {
        const int e = (((const ushort_t*)x)[2 * tid] >> 7) & 0xFF;
        const unsigned long long m = __ballot(e >= 100 && e <= 140);
        if ((tid & 63) == 0) cnts[tid >> 6] = (int)__popcll(m);
    }
    __syncthreads();
    const int am = (cnts[0] + cnts[1] + cnts[2] + cnts[3]) >= 128 ? 1 : 0;
    const int bid = blockIdx.x;
    if (bid < 4096) {
        const int z = bid >> 10, b10 = bid & 1023;
        const void* in = (z == 0) ? w0 : (z == 1) ? w1 : (z == 2) ? w2 : w3;
        ushort_t*  out = (z == 0) ? WqkvT : (z == 1) ? (WqkvT + (1u << 20))
                       : (z == 2) ? (WqkvT + 2u * (1u << 20)) : WoT;
        const int bx = (b10 & 31) * 32, by = (b10 >> 5) * 32;
        const int tx = tid & 31, ty = tid >> 5;
        #pragma unroll
        for (int r = ty; r < 32; r += 8) {
            const size_t idx = (size_t)(by + r) * CH + bx + tx;
            tile[r][tx] = am ? ((const ushort_t*)in)[idx] : f2b(((const float*)in)[idx]);
        }
        __syncthreads();
        #pragma unroll
        for (int r = ty; r < 32; r += 8)
            out[(size_t)(bx + r) * CH + by + tx] = tile[tx][r];
    } else if (bid < 4112) {
        const int i = (bid - 4096) * 256 + tid;  // 0..4095
        const int m = i >> 10, idx = i & 1023;
        const void* in = (m == 0) ? b0 : (m == 1) ? b1 : (m == 2) ? b2 : b3;
        biasC[i] = am ? ((const ushort_t*)in)[idx] : f2b(((const float*)in)[idx]);
        if (i == 0) *flagOut = am;
    } else {
        const int i = ((bid - 4112) * 256 + tid) * 8;
        if (am) {
            *(float4*)&xb[i] = *(const float4*)&((const ushort_t*)x)[i];
        } else {
            const float* p = (const float*)x + i;
            float4 f0 = *(const float4*)p;
            float4 f1 = *(const float4*)(p + 4);
            ushort_t t[8] = {f2b(f0.x), f2b(f0.y), f2b(f0.z), f2b(f0.w),
                             f2b(f1.x), f2b(f1.y), f2b(f1.z), f2b(f1.w)};
            *(float4*)&xb[i] = *(const float4*)t;
        }
    }
}

// ======== 256x128 triple-buffered phase pipeline (R5-proven + stage-earlier) =====
// R5 structure (71.3 us qkv, verified). R6's single delta here: ALL 6 of tile
// t+2's loads issue at phase kk=0 (was 3+3 across kk=0/1). The tile-end
// vmcnt(6) gate then waits on loads issued 4 phases (~1200 cyc) earlier instead
// of 2 (~500 cyc) — covering the ~900-cyc HBM-miss latency (m126). R6's BK=32
// regression (88 us) is consistent: its gated loads were even younger.
// Sync proof unchanged from R5: same buffers, barriers, gate positions/counts;
// only the ISSUE position of 3 loads moves within tile t, still after the
// start-of-tile-t barrier that followed the gate proving buf (t+2)%3 free.
__device__ __forceinline__ void pipe256x128(const ushort_t* __restrict__ A,
                                            const ushort_t* __restrict__ Bt,
                                            int row0, int col0,
                                            ushort_t* __restrict__ As,   // [3][256*64]
                                            ushort_t* __restrict__ Bs,   // [3][128*64]
                                            floatx4 acc[4][4], int tid) {
    const int lane = tid & 63, wave = tid >> 6;
    const int lane15 = lane & 15, quad = lane >> 4;
    const int s7 = lane15 & 7;                       // read-side swizzle key
    const int wm = wave >> 1, wn = wave & 1;         // 4M x 2N wave grid
    const int lrow = lane >> 3, lu = lane & 7, gu = lu ^ lrow;          // A staging
    const int brow = tid >> 3, bu = tid & 7, bgu = bu ^ (brow & 7);     // B staging

    auto stage_part = [&](int buf, int tt, int h) {
        ushort_t* Ad = As + buf * (256 * 64) + (h * 128 + wave * 16 + lrow) * 64 + lu * 8;
        const ushort_t* Asrc = A + (size_t)(row0 + h * 128 + wave * 16 + lrow) * CH + tt * 64 + gu * 8;
        GLD16(Asrc, Ad);
        GLD16(Asrc + 8 * CH, Ad + 8 * 64);           // row+8: same &7 -> same gu
        ushort_t* Bd = Bs + buf * (128 * 64) + (h * 64 + brow) * 64 + bu * 8;
        const ushort_t* Bsrc = Bt + (size_t)(col0 + h * 64 + brow) * CH + tt * 64 + bgu * 8;
        GLD16(Bsrc, Bd);
    };

    stage_part(0, 0, 0); stage_part(0, 0, 1);
    stage_part(1, 1, 0); stage_part(1, 1, 1);
    asm volatile("s_waitcnt vmcnt(6)" ::: "memory");  // tile 0's 6 landed
    __builtin_amdgcn_s_barrier();

    int buf = 0;
    for (int t = 0; t < 16; ++t) {
        const ushort_t* Ab = As + buf * (256 * 64) + (wm * 64) * 64;
        const ushort_t* Bb = Bs + buf * (128 * 64) + (wn * 64) * 64;
        int bnext = buf + 2; if (bnext >= 3) bnext -= 3;
        const bool pf = (t + 2 < 16);
        #pragma unroll
        for (int kk = 0; kk < 2; ++kk) {
            short8 af[4], bfr[4];
            #pragma unroll
            for (int i = 0; i < 4; i++)
                af[i] = *(const short8*)&Ab[(i * 16 + lane15) * 64 + (((kk * 4 + quad) ^ s7) * 8)];
            #pragma unroll
            for (int j = 0; j < 4; j++)
                bfr[j] = *(const short8*)&Bb[(j * 16 + lane15) * 64 + (((kk * 4 + quad) ^ s7) * 8)];
            if (kk == 0 && pf) {                      // stage ALL of t+2 early
                stage_part(bnext, t + 2, 0);
                stage_part(bnext, t + 2, 1);
            }
            __builtin_amdgcn_s_barrier();
            __builtin_amdgcn_s_setprio(1);
            #pragma unroll
            for (int i = 0; i < 4; i++)
                #pragma unroll
                for (int j = 0; j < 4; j++)
                    acc[i][j] = __builtin_amdgcn_mfma_f32_16x16x32_bf16(af[i], bfr[j], acc[i][j], 0, 0, 0);
            __builtin_amdgcn_s_setprio(0);
            if (kk == 1 && t < 15) {
                if (pf) asm volatile("s_waitcnt vmcnt(6)" ::: "memory");
                else    asm volatile("s_waitcnt vmcnt(0)" ::: "memory");  // t=14 drain
            }
            __builtin_amdgcn_s_barrier();
        }
        buf = (buf == 2) ? 0 : buf + 1;
    }
}

// ---------------- fused QKV GEMM: [8192,1024] @ [3072,1024]^T + bias -------------
__global__ __launch_bounds__(512) void gemm_qkv8(const ushort_t* __restrict__ A,
                                                 const ushort_t* __restrict__ Bt,
                                                 const ushort_t* __restrict__ bias,
                                                 ushort_t* __restrict__ Qb,
                                                 ushort_t* __restrict__ Kb,
                                                 ushort_t* __restrict__ Vt,
                                                 float qscale) {
    __shared__ __align__(16) ushort_t As[3 * 256 * 64];   // 96 KB
    __shared__ __align__(16) ushort_t Bs[3 * 128 * 64];   // 48 KB
    const int tid = threadIdx.x;
    const int lane = tid & 63, wave = tid >> 6;
    const int lane15 = lane & 15, quad = lane >> 4;
    const int wm = wave >> 1, wn = wave & 1;
    // XCD-chunked bijective swizzle (grid 768, 768%8==0, cpx=96); col-fastest
    // within an XCD so consecutive blocks share the A panel (L2 hits).
    const int bid = blockIdx.x;
    const int bidl = (bid & 7) * 96 + (bid >> 3);
    const int rowblk = bidl / 24, colblk = bidl - rowblk * 24;
    const int row0 = rowblk * 256, col0 = colblk * 128;
    const int seg = col0 >> 10;                      // 0=Q 1=K 2=V (block-uniform)

    floatx4 acc[4][4];
    #pragma unroll
    for (int i = 0; i < 4; i++)
        #pragma unroll
        for (int j = 0; j < 4; j++) acc[i][j] = {0.f, 0.f, 0.f, 0.f};

    pipe256x128(A, Bt, row0, col0, As, Bs, acc, tid);

    #pragma unroll
    for (int j = 0; j < 4; j++) {
        const int col = col0 + wn * 64 + j * 16 + lane15;
        const float bv = b2f(bias[col]);
        #pragma unroll
        for (int i = 0; i < 4; i++) {
            const int rowb = row0 + wm * 64 + i * 16 + quad * 4;
            if (seg == 0) {
                #pragma unroll
                for (int r = 0; r < 4; r++)
                    Qb[(size_t)(rowb + r) * CH + col] = f2b((acc[i][j][r] + bv) * qscale);
            } else if (seg == 1) {
                const int c = col - 1024;
                #pragma unroll
                for (int r = 0; r < 4; r++)
                    Kb[(size_t)(rowb + r) * CH + c] = f2b(acc[i][j][r] + bv);
            } else {
                const int c = col - 2048;
                ushort_t pk[4];
                #pragma unroll
                for (int r = 0; r < 4; r++) pk[r] = f2b(acc[i][j][r] + bv);
                const int bb = rowb >> 11, tc = rowb & 2047;
                *(uint2*)&Vt[((size_t)bb * 1024 + c) * 2048 + tc] = *(const uint2*)pk;
            }
        }
    }
}

// ---------------- output GEMM: Out[8192,1024] = A @ WoT^T + bias -----------------
__global__ __launch_bounds__(512) void gemm_bt8(const ushort_t* __restrict__ A,
                                                const ushort_t* __restrict__ Bt,
                                                const ushort_t* __restrict__ bias,
                                                void* __restrict__ Out,
                                                const int* __restrict__ oflag) {
    __shared__ __align__(16) ushort_t As[3 * 256 * 64];   // 96 KB
    __shared__ __align__(16) ushort_t Bs[3 * 128 * 64];   // 48 KB
    const int om = *oflag;
    const int tid = threadIdx.x;
    const int lane = tid & 63, wave = tid >> 6;
    const int lane15 = lane & 15, quad = lane >> 4;
    const int wm = wave >> 1, wn = wave & 1;
    // grid 256 = exactly 1 round; cpx = 32
    const int bid = blockIdx.x;
    const int bidl = (bid & 7) * 32 + (bid >> 3);
    const int rowblk = bidl >> 3, colblk = bidl & 7;
    const int row0 = rowblk * 256, col0 = colblk * 128;

    floatx4 acc[4][4];
    #pragma unroll
    for (int i = 0; i < 4; i++)
        #pragma unroll
        for (int j = 0; j < 4; j++) acc[i][j] = {0.f, 0.f, 0.f, 0.f};

    pipe256x128(A, Bt, row0, col0, As, Bs, acc, tid);

    #pragma unroll
    for (int j = 0; j < 4; j++) {
        const int col = col0 + wn * 64 + j * 16 + lane15;
        const float bv = b2f(bias[col]);
        #pragma unroll
        for (int i = 0; i < 4; i++) {
            const int rowb = row0 + wm * 64 + i * 16 + quad * 4;
            #pragma unroll
            for (int r = 0; r < 4; r++) {
                const float val = acc[i][j][r] + bv;
                const size_t idx = (size_t)(rowb + r) * CH + col;
                if (om) ((ushort_t*)Out)[idx] = f2b(val);
                else    ((float*)Out)[idx] = val;
            }
        }
    }
}

// ---------------- flash attention (round-6 structure + S^T write path) -----------
// Keep: K/V dbuf, one barrier per tile, XCD-local (b,h) in bid&63, ones-MFMA
// rowsum, exp2 with scale folded into Q, swizzled K/V staging, Ps LDS round
// trip (decouples S from PV across waves). DO NOT add a second
// __launch_bounds__ arg (round-7 spill).
// R1 (kept): fast_exp2 raw v_exp_f32; Ps stride-64 4-bit XOR chunk swizzle
// (b64 writes and split-b64 PV reads both bank-conflict-free).
__global__ __launch_bounds__(256) void attn_fwd(ushort_t* __restrict__ QY,
                                                const ushort_t* __restrict__ K,
                                                const ushort_t* __restrict__ Vt) {
    __shared__ __align__(16) ushort_t Ks[2][64 * 64];    // [buf][kv][d], swizzled
    __shared__ __align__(16) ushort_t Vs[2][64 * 64];    // [buf][d][kv], swizzled
    __shared__ __align__(16) ushort_t Ps[4 * 32 * 64];   // per-wave [q=32][kv=64], XOR-swizzled
    const int tid = threadIdx.x;
    const int lane = tid & 63, wave = tid >> 6;
    const int lane15 = lane & 15, quad = lane >> 4;
    const int sw = lane15 & 7;                            // read-side swizzle key
    const int bid = blockIdx.x;
    const int hb = bid & 63, qslot = bid >> 6;
    const int qb = 15 - qslot;
    const int h = hb & 15, b = hb >> 4;
    const int q0 = qb * 128;
    const size_t baseR = (size_t)b * SEQ * CH + h * HSZ;      // +t*CH+d (Q,K,Y)
    const size_t baseV = ((size_t)b * 1024 + h * HSZ) * SEQ;  // +d*SEQ+t (Vt)
    const int rg = lane >> 3, cg = (lane & 7) ^ rg;           // staging swizzle
    const int psBase = wave * 2048;                           // per-wave Ps region

    short8 qf[2][2];
    #pragma unroll
    for (int mm = 0; mm < 2; mm++) {
        const ushort_t* qp = QY + baseR + (size_t)(q0 + wave * 32 + mm * 16 + lane15) * CH + quad * 8;
        qf[mm][0] = *(const short8*)qp;
        qf[mm][1] = *(const short8*)(qp + 32);
    }
    const short8 kOnes = (short8)(short)0x3F80;  // bf16 1.0 x8

    floatx4 o[2][5];  // [mm][0..3]=O d-chunks, [4]=l (rowsum)
    #pragma unroll
    for (int mm = 0; mm < 2; mm++)
        #pragma unroll
        for (int j = 0; j < 5; j++) o[mm][j] = {0.f, 0.f, 0.f, 0.f};

    const int nkt = 2 * qb + 2;
    // preamble: stage tile 0 into buf 0
    #pragma unroll
    for (int l = wave; l < 8; l += 4) {
        GLD16(K  + baseR + (size_t)(l * 8 + rg) * CH + cg * 8, &Ks[0][l * 512]);
        GLD16(Vt + baseV + (size_t)(l * 8 + rg) * SEQ + cg * 8, &Vs[0][l * 512]);
    }

    for (int kt = 0; kt < nkt; kt++) {
        __syncthreads();  // staging of kt landed; all waves done with buf kt^1
        const int cur = kt & 1;
        if (kt + 1 < nkt) {
            const int kv1 = (kt + 1) * 64, nb = cur ^ 1;
            #pragma unroll
            for (int l = wave; l < 8; l += 4) {
                GLD16(K  + baseR + (size_t)(kv1 + l * 8 + rg) * CH + cg * 8, &Ks[nb][l * 512]);
                GLD16(Vt + baseV + (size_t)(l * 8 + rg) * SEQ + kv1 + cg * 8, &Vs[nb][l * 512]);
            }
        }
        const int kv0 = kt * 64;
        const int masked = (kt >= 2 * qb);

        // K fragments shared by both q-groups: a-frag of S^T = K[kv][d]
        short8 kf[4][2];
        #pragma unroll
        for (int g = 0; g < 4; g++) {
            kf[g][0] = *(const short8*)&Ks[cur][(g * 16 + lane15) * 64 + ((quad ^ sw) * 8)];
            kf[g][1] = *(const short8*)&Ks[cur][(g * 16 + lane15) * 64 + (((quad + 4) ^ sw) * 8)];
        }

        #pragma unroll
        for (int mm = 0; mm < 2; mm++) {
            const int qrow = q0 + wave * 32 + mm * 16 + lane15;
            const int rowOff = psBase + (mm * 16 + lane15) * 64;
            #pragma unroll
            for (int g = 0; g < 4; g++) {
                // z = S^T[kv = kv0+g*16+quad*4+r][q = qrow]
                floatx4 z = {0.f, 0.f, 0.f, 0.f};
                z = __builtin_amdgcn_mfma_f32_16x16x32_bf16(kf[g][0], qf[mm][0], z, 0, 0, 0);
                z = __builtin_amdgcn_mfma_f32_16x16x32_bf16(kf[g][1], qf[mm][1], z, 0, 0, 0);
                if (masked) {
                    #pragma unroll
                    for (int r = 0; r < 4; r++) {
                        const int col = kv0 + g * 16 + quad * 4 + r;
                        z[r] = (col <= qrow) ? z[r] : -1e30f;
                    }
                }
                // p = 2^z (raw v_exp_f32: 2^-1e30 -> 0 for masked lanes)
                const float p0 = fast_exp2(z[0]), p1 = fast_exp2(z[1]);
                const float p2 = fast_exp2(z[2]), p3 = fast_exp2(z[3]);
                unsigned int lo, hi;
                asm("v_cvt_pk_bf16_f32 %0, %1, %2" : "=v"(lo) : "v"(p0), "v"(p1));
                asm("v_cvt_pk_bf16_f32 %0, %1, %2" : "=v"(hi) : "v"(p2), "v"(p3));
                uint2 w; w.x = lo; w.y = hi;
                // logical 8B-chunk c = g*4+quad; physical = c ^ (row&15)
                *(uint2*)&Ps[rowOff + (((g * 4 + quad) ^ lane15) * 4)] = w;
            }
        }
        // Ps wave-private: lgkmcnt auto-wait orders write->read, no barrier

        #pragma unroll
        for (int kk = 0; kk < 2; kk++) {
            #pragma unroll
            for (int mm = 0; mm < 2; mm++) {
                // A-frag: logical chunks c0 = kk*8+quad*2, c0+1; swizzled apart
                const int rowOff = psBase + (mm * 16 + lane15) * 64;
                const int c0 = kk * 8 + quad * 2;
                short8 a;
                ((uint2*)&a)[0] = *(const uint2*)&Ps[rowOff + (((c0    ) ^ lane15) * 4)];
                ((uint2*)&a)[1] = *(const uint2*)&Ps[rowOff + (((c0 + 1) ^ lane15) * 4)];
                #pragma unroll
                for (int jn = 0; jn < 4; jn++) {
                    short8 bb = *(const short8*)&Vs[cur][(jn * 16 + lane15) * 64 + (((kk * 4 + quad) ^ sw) * 8)];
                    o[mm][jn] = __builtin_amdgcn_mfma_f32_16x16x32_bf16(a, bb, o[mm][jn], 0, 0, 0);
                }
                o[mm][4] = __builtin_amdgcn_mfma_f32_16x16x32_bf16(a, kOnes, o[mm][4], 0, 0, 0);
            }
        }
    }

    // epilogue: Y = O / l
    #pragma unroll
    for (int mm = 0; mm < 2; mm++)
        #pragma unroll
        for (int r = 0; r < 4; r++) {
            const int qrow = q0 + wave * 32 + mm * 16 + quad * 4 + r;
            const float rinv = 1.0f / fmaxf(o[mm][4][r], 1e-30f);
            #pragma unroll
            for (int jn = 0; jn < 4; jn++)
                QY[baseR + (size_t)qrow * CH + jn * 16 + lane15] = f2b(o[mm][jn][r] * rinv);
        }
}

extern "C" void kernel_launch(void* const* d_in, const int* in_sizes, int n_in,
                              void* d_out, int out_size, void* d_ws, size_t ws_size,
                              hipStream_t stream) {
    const void* x  = d_in[0];
    const void* Wk = d_in[1];
    const void* bk = d_in[2];
    const void* Wq = d_in[3];
    const void* bq = d_in[4];
    const void* Wv = d_in[5];
    const void* bv = d_in[6];
    const void* Wo = d_in[7];
    const void* bo = d_in[8];

    ushort_t* ws    = (ushort_t*)d_ws;
    int*      flag  = (int*)d_ws;
    ushort_t* biasC = ws + 2048;                    // 4x1024: q,k,v,o (contiguous)
    ushort_t* WqkvT = ws + 32768;                   // 3x1M contiguous: q,k,v
    ushort_t* WoT   = WqkvT + 3u * (1u << 20);
    ushort_t* xb    = ws + 4227072;                 // 8M elems bf16
    ushort_t* Qb    = ws + 12615680;                // 8M elems (becomes Y)
    ushort_t* Kb    = (ushort_t*)d_out;             // d_out scratch until final GEMM
    ushort_t* VtB   = Kb + (size_t)MROWS * CH;

    // one fused prep kernel: detect + weights + bias + x (was 4 launches)
    prep_all<<<dim3(8208), 256, 0, stream>>>(x, Wq, Wk, Wv, Wo, bq, bk, bv, bo,
                                             WqkvT, WoT, biasC, xb, flag);

    // scale = (1/sqrt(64)) * log2(e), folded into Q so attention uses exp2
    gemm_qkv8<<<dim3(768), 512, 0, stream>>>(xb, WqkvT, biasC, Qb, Kb, VtB, 0.1803368801f);

    attn_fwd<<<dim3(1024), 256, 0, stream>>>(Qb, Kb, VtB);

    gemm_bt8<<<dim3(256), 512, 0, stream>>>(Qb, WoT, biasC + 3072, d_out, flag);
}

// Round 9
// 239.433 us; speedup vs baseline: 1.0797x; 1.0433x over previous
//
#include <hip/hip_runtime.h>
#include <hip/hip_bf16.h>

typedef unsigned short ushort_t;
typedef __attribute__((ext_vector_type(8))) short short8;   // 8 x bf16 (4 VGPRs)
typedef __attribute__((ext_vector_type(4))) float floatx4;  // MFMA acc

#define BATCH 4
#define SEQ   2048
#define CH    1024
#define NHEAD 16
#define HSZ   64
#define MROWS (BATCH * SEQ)  // 8192

// async global->LDS, 16B per lane; LDS dest = wave-uniform base + lane*16
#define GLD16(gptr, lptr) \
    __builtin_amdgcn_global_load_lds((const __attribute__((address_space(1))) unsigned int*)(gptr), \
                                     (__attribute__((address_space(3))) unsigned int*)(lptr), 16, 0, 0)

__device__ inline ushort_t f2b(float f) {
    __hip_bfloat16 h = __float2bfloat16(f);
    return *(ushort_t*)&h;
}
__device__ inline float b2f(ushort_t u) {
    return __bfloat162float(*(__hip_bfloat16*)&u);
}

// raw v_exp_f32: OCML exp2f adds a denormal-range guard (~5 VALU insts/call)
// we don't need — masked inputs are -1e30 and raw v_exp_f32(-1e30) = +0.
__device__ __forceinline__ float fast_exp2(float x) {
#if __has_builtin(__builtin_amdgcn_exp2f)
    return __builtin_amdgcn_exp2f(x);
#else
    float r; asm("v_exp_f32 %0, %1" : "=v"(r) : "v"(x)); return r;
#endif
}

// ======== fused prep: dtype detect + weight transpose + bias + x convert =========
// Per-block dtype self-detect from x's first 512 B (256 samples, threshold 128).
// R9: when input is already bf16, the x-convert blocks EXIT — gemm_qkv8 reads x
// directly (saves 32 MB of HBM traffic for a no-op copy). f32 path unchanged.
__global__ __launch_bounds__(256) void prep_all(const void* __restrict__ x,
        const void* __restrict__ w0, const void* __restrict__ w1,
        const void* __restrict__ w2, const void* __restrict__ w3,
        const void* __restrict__ b0, const void* __restrict__ b1,
        const void* __restrict__ b2, const void* __restrict__ b3,
        ushort_t* __restrict__ WqkvT, ushort_t* __restrict__ WoT,
        ushort_t* __restrict__ biasC, ushort_t* __restrict__ xb,
        int* __restrict__ flagOut) {
    __shared__ int cnts[4];
    __shared__ ushort_t tile[32][33];
    const int tid = threadIdx.x;
    {
        const int e = (((const ushort_t*)x)[2 * tid] >> 7) & 0xFF;
        const unsigned long long m = __ballot(e >= 100 && e <= 140);
        if ((tid & 63) == 0) cnts[tid >> 6] = (int)__popcll(m);
    }
    __syncthreads();
    const int am = (cnts[0] + cnts[1] + cnts[2] + cnts[3]) >= 128 ? 1 : 0;
    const int bid = blockIdx.x;
    if (bid < 4096) {
        const int z = bid >> 10, b10 = bid & 1023;
        const void* in = (z == 0) ? w0 : (z == 1) ? w1 : (z == 2) ? w2 : w3;
        ushort_t*  out = (z == 0) ? WqkvT : (z == 1) ? (WqkvT + (1u << 20))
                       : (z == 2) ? (WqkvT + 2u * (1u << 20)) : WoT;
        const int bx = (b10 & 31) * 32, by = (b10 >> 5) * 32;
        const int tx = tid & 31, ty = tid >> 5;
        #pragma unroll
        for (int r = ty; r < 32; r += 8) {
            const size_t idx = (size_t)(by + r) * CH + bx + tx;
            tile[r][tx] = am ? ((const ushort_t*)in)[idx] : f2b(((const float*)in)[idx]);
        }
        __syncthreads();
        #pragma unroll
        for (int r = ty; r < 32; r += 8)
            out[(size_t)(bx + r) * CH + by + tx] = tile[tx][r];
    } else if (bid < 4112) {
        const int i = (bid - 4096) * 256 + tid;  // 0..4095
        const int m = i >> 10, idx = i & 1023;
        const void* in = (m == 0) ? b0 : (m == 1) ? b1 : (m == 2) ? b2 : b3;
        biasC[i] = am ? ((const ushort_t*)in)[idx] : f2b(((const float*)in)[idx]);
        if (i == 0) *flagOut = am;
    } else {
        if (am) return;  // bf16 input: gemm reads x directly, no copy needed
        const int i = ((bid - 4112) * 256 + tid) * 8;
        const float* p = (const float*)x + i;
        float4 f0 = *(const float4*)p;
        float4 f1 = *(const float4*)(p + 4);
        ushort_t t[8] = {f2b(f0.x), f2b(f0.y), f2b(f0.z), f2b(f0.w),
                         f2b(f1.x), f2b(f1.y), f2b(f1.z), f2b(f1.w)};
        *(float4*)&xb[i] = *(const float4*)t;
    }
}

// ======== 256x128 triple-buffered phase pipeline (R5-proven, 71.3 us) ============
// R7's "stage all 6 at kk=0" REGRESSED (76.8, MfmaUtil 27): bunched stores
// lengthen one phase more than the older gate helps. This is the exact R5 form:
// per phase kk, ds_reads pre-barrier, then stage_part(t+2, kk) (3 loads), MFMA
// under setprio, counted vmcnt(6) gate only at tile end, vmcnt(0) only at t=14.
__device__ __forceinline__ void pipe256x128(const ushort_t* __restrict__ A,
                                            const ushort_t* __restrict__ Bt,
                                            int row0, int col0,
                                            ushort_t* __restrict__ As,   // [3][256*64]
                                            ushort_t* __restrict__ Bs,   // [3][128*64]
                                            floatx4 acc[4][4], int tid) {
    const int lane = tid & 63, wave = tid >> 6;
    const int lane15 = lane & 15, quad = lane >> 4;
    const int s7 = lane15 & 7;                       // read-side swizzle key
    const int wm = wave >> 1, wn = wave & 1;         // 4M x 2N wave grid
    const int lrow = lane >> 3, lu = lane & 7, gu = lu ^ lrow;          // A staging
    const int brow = tid >> 3, bu = tid & 7, bgu = bu ^ (brow & 7);     // B staging

    auto stage_part = [&](int buf, int tt, int h) {
        ushort_t* Ad = As + buf * (256 * 64) + (h * 128 + wave * 16 + lrow) * 64 + lu * 8;
        const ushort_t* Asrc = A + (size_t)(row0 + h * 128 + wave * 16 + lrow) * CH + tt * 64 + gu * 8;
        GLD16(Asrc, Ad);
        GLD16(Asrc + 8 * CH, Ad + 8 * 64);           // row+8: same &7 -> same gu
        ushort_t* Bd = Bs + buf * (128 * 64) + (h * 64 + brow) * 64 + bu * 8;
        const ushort_t* Bsrc = Bt + (size_t)(col0 + h * 64 + brow) * CH + tt * 64 + bgu * 8;
        GLD16(Bsrc, Bd);
    };

    stage_part(0, 0, 0); stage_part(0, 0, 1);
    stage_part(1, 1, 0); stage_part(1, 1, 1);
    asm volatile("s_waitcnt vmcnt(6)" ::: "memory");  // tile 0's 6 landed
    __builtin_amdgcn_s_barrier();

    int buf = 0;
    for (int t = 0; t < 16; ++t) {
        const ushort_t* Ab = As + buf * (256 * 64) + (wm * 64) * 64;
        const ushort_t* Bb = Bs + buf * (128 * 64) + (wn * 64) * 64;
        int bnext = buf + 2; if (bnext >= 3) bnext -= 3;
        const bool pf = (t + 2 < 16);
        #pragma unroll
        for (int kk = 0; kk < 2; ++kk) {
            short8 af[4], bfr[4];
            #pragma unroll
            for (int i = 0; i < 4; i++)
                af[i] = *(const short8*)&Ab[(i * 16 + lane15) * 64 + (((kk * 4 + quad) ^ s7) * 8)];
            #pragma unroll
            for (int j = 0; j < 4; j++)
                bfr[j] = *(const short8*)&Bb[(j * 16 + lane15) * 64 + (((kk * 4 + quad) ^ s7) * 8)];
            if (pf) stage_part(bnext, t + 2, kk);
            __builtin_amdgcn_s_barrier();
            __builtin_amdgcn_s_setprio(1);
            #pragma unroll
            for (int i = 0; i < 4; i++)
                #pragma unroll
                for (int j = 0; j < 4; j++)
                    acc[i][j] = __builtin_amdgcn_mfma_f32_16x16x32_bf16(af[i], bfr[j], acc[i][j], 0, 0, 0);
            __builtin_amdgcn_s_setprio(0);
            if (kk == 1 && t < 15) {
                if (pf) asm volatile("s_waitcnt vmcnt(6)" ::: "memory");
                else    asm volatile("s_waitcnt vmcnt(0)" ::: "memory");  // t=14 drain
            }
            __builtin_amdgcn_s_barrier();
        }
        buf = (buf == 2) ? 0 : buf + 1;
    }
}

// ---------------- fused QKV GEMM: [8192,1024] @ [3072,1024]^T + bias -------------
// R9: A operand selected at runtime — raw x when input is bf16 (skips the copy),
// xb (converted) when f32. Uniform scalar-load branch, zero schedule change.
__global__ __launch_bounds__(512) void gemm_qkv8(const void* __restrict__ xraw,
                                                 const ushort_t* __restrict__ xb,
                                                 const int* __restrict__ xflag,
                                                 const ushort_t* __restrict__ Bt,
                                                 const ushort_t* __restrict__ bias,
                                                 ushort_t* __restrict__ Qb,
                                                 ushort_t* __restrict__ Kb,
                                                 ushort_t* __restrict__ Vt,
                                                 float qscale) {
    __shared__ __align__(16) ushort_t As[3 * 256 * 64];   // 96 KB
    __shared__ __align__(16) ushort_t Bs[3 * 128 * 64];   // 48 KB
    const ushort_t* A = (*xflag) ? (const ushort_t*)xraw : xb;
    const int tid = threadIdx.x;
    const int lane = tid & 63, wave = tid >> 6;
    const int lane15 = lane & 15, quad = lane >> 4;
    const int wm = wave >> 1, wn = wave & 1;
    // XCD-chunked bijective swizzle (grid 768, 768%8==0, cpx=96); col-fastest
    // within an XCD so consecutive blocks share the A panel (L2 hits).
    const int bid = blockIdx.x;
    const int bidl = (bid & 7) * 96 + (bid >> 3);
    const int rowblk = bidl / 24, colblk = bidl - rowblk * 24;
    const int row0 = rowblk * 256, col0 = colblk * 128;
    const int seg = col0 >> 10;                      // 0=Q 1=K 2=V (block-uniform)

    floatx4 acc[4][4];
    #pragma unroll
    for (int i = 0; i < 4; i++)
        #pragma unroll
        for (int j = 0; j < 4; j++) acc[i][j] = {0.f, 0.f, 0.f, 0.f};

    pipe256x128(A, Bt, row0, col0, As, Bs, acc, tid);

    #pragma unroll
    for (int j = 0; j < 4; j++) {
        const int col = col0 + wn * 64 + j * 16 + lane15;
        const float bv = b2f(bias[col]);
        #pragma unroll
        for (int i = 0; i < 4; i++) {
            const int rowb = row0 + wm * 64 + i * 16 + quad * 4;
            if (seg == 0) {
                #pragma unroll
                for (int r = 0; r < 4; r++)
                    Qb[(size_t)(rowb + r) * CH + col] = f2b((acc[i][j][r] + bv) * qscale);
            } else if (seg == 1) {
                const int c = col - 1024;
                #pragma unroll
                for (int r = 0; r < 4; r++)
                    Kb[(size_t)(rowb + r) * CH + c] = f2b(acc[i][j][r] + bv);
            } else {
                const int c = col - 2048;
                ushort_t pk[4];
                #pragma unroll
                for (int r = 0; r < 4; r++) pk[r] = f2b(acc[i][j][r] + bv);
                const int bb = rowb >> 11, tc = rowb & 2047;
                *(uint2*)&Vt[((size_t)bb * 1024 + c) * 2048 + tc] = *(const uint2*)pk;
            }
        }
    }
}

// ---------------- output GEMM: Out[8192,1024] = A @ WoT^T + bias -----------------
__global__ __launch_bounds__(512) void gemm_bt8(const ushort_t* __restrict__ A,
                                                const ushort_t* __restrict__ Bt,
                                                const ushort_t* __restrict__ bias,
                                                void* __restrict__ Out,
                                                const int* __restrict__ oflag) {
    __shared__ __align__(16) ushort_t As[3 * 256 * 64];   // 96 KB
    __shared__ __align__(16) ushort_t Bs[3 * 128 * 64];   // 48 KB
    const int om = *oflag;
    const int tid = threadIdx.x;
    const int lane = tid & 63, wave = tid >> 6;
    const int lane15 = lane & 15, quad = lane >> 4;
    const int wm = wave >> 1, wn = wave & 1;
    // grid 256 = exactly 1 round; cpx = 32
    const int bid = blockIdx.x;
    const int bidl = (bid & 7) * 32 + (bid >> 3);
    const int rowblk = bidl >> 3, colblk = bidl & 7;
    const int row0 = rowblk * 256, col0 = colblk * 128;

    floatx4 acc[4][4];
    #pragma unroll
    for (int i = 0; i < 4; i++)
        #pragma unroll
        for (int j = 0; j < 4; j++) acc[i][j] = {0.f, 0.f, 0.f, 0.f};

    pipe256x128(A, Bt, row0, col0, As, Bs, acc, tid);

    #pragma unroll
    for (int j = 0; j < 4; j++) {
        const int col = col0 + wn * 64 + j * 16 + lane15;
        const float bv = b2f(bias[col]);
        #pragma unroll
        for (int i = 0; i < 4; i++) {
            const int rowb = row0 + wm * 64 + i * 16 + quad * 4;
            #pragma unroll
            for (int r = 0; r < 4; r++) {
                const float val = acc[i][j][r] + bv;
                const size_t idx = (size_t)(rowb + r) * CH + col;
                if (om) ((ushort_t*)Out)[idx] = f2b(val);
                else    ((float*)Out)[idx] = val;
            }
        }
    }
}

// ---------------- flash attention (R7-proven single-pass form) -------------------
// R8's equal-work pairing NaN'd; defect not identified by inspection -> reverted
// per rigor rules (no blind iteration on correctness failures). This is the exact
// R2..R7-verified kernel: fast_exp2, S^T write path, Ps stride-64 XOR swizzle,
// K/V dbuf, one barrier per tile, ones-MFMA rowsum, XCD-local (b,h) in bid&63.
// DO NOT add a second __launch_bounds__ arg (round-7 spill).
__global__ __launch_bounds__(256) void attn_fwd(ushort_t* __restrict__ QY,
                                                const ushort_t* __restrict__ K,
                                                const ushort_t* __restrict__ Vt) {
    __shared__ __align__(16) ushort_t Ks[2][64 * 64];    // [buf][kv][d], swizzled
    __shared__ __align__(16) ushort_t Vs[2][64 * 64];    // [buf][d][kv], swizzled
    __shared__ __align__(16) ushort_t Ps[4 * 32 * 64];   // per-wave [q=32][kv=64], XOR-swizzled
    const int tid = threadIdx.x;
    const int lane = tid & 63, wave = tid >> 6;
    const int lane15 = lane & 15, quad = lane >> 4;
    const int sw = lane15 & 7;                            // read-side swizzle key
    const int bid = blockIdx.x;
    const int hb = bid & 63, qslot = bid >> 6;
    const int qb = 15 - qslot;
    const int h = hb & 15, b = hb >> 4;
    const int q0 = qb * 128;
    const size_t baseR = (size_t)b * SEQ * CH + h * HSZ;      // +t*CH+d (Q,K,Y)
    const size_t baseV = ((size_t)b * 1024 + h * HSZ) * SEQ;  // +d*SEQ+t (Vt)
    const int rg = lane >> 3, cg = (lane & 7) ^ rg;           // staging swizzle
    const int psBase = wave * 2048;                           // per-wave Ps region

    short8 qf[2][2];
    #pragma unroll
    for (int mm = 0; mm < 2; mm++) {
        const ushort_t* qp = QY + baseR + (size_t)(q0 + wave * 32 + mm * 16 + lane15) * CH + quad * 8;
        qf[mm][0] = *(const short8*)qp;
        qf[mm][1] = *(const short8*)(qp + 32);
    }
    const short8 kOnes = (short8)(short)0x3F80;  // bf16 1.0 x8

    floatx4 o[2][5];  // [mm][0..3]=O d-chunks, [4]=l (rowsum)
    #pragma unroll
    for (int mm = 0; mm < 2; mm++)
        #pragma unroll
        for (int j = 0; j < 5; j++) o[mm][j] = {0.f, 0.f, 0.f, 0.f};

    const int nkt = 2 * qb + 2;
    // preamble: stage tile 0 into buf 0
    #pragma unroll
    for (int l = wave; l < 8; l += 4) {
        GLD16(K  + baseR + (size_t)(l * 8 + rg) * CH + cg * 8, &Ks[0][l * 512]);
        GLD16(Vt + baseV + (size_t)(l * 8 + rg) * SEQ + cg * 8, &Vs[0][l * 512]);
    }

    for (int kt = 0; kt < nkt; kt++) {
        __syncthreads();  // staging of kt landed; all waves done with buf kt^1
        const int cur = kt & 1;
        if (kt + 1 < nkt) {
            const int kv1 = (kt + 1) * 64, nb = cur ^ 1;
            #pragma unroll
            for (int l = wave; l < 8; l += 4) {
                GLD16(K  + baseR + (size_t)(kv1 + l * 8 + rg) * CH + cg * 8, &Ks[nb][l * 512]);
                GLD16(Vt + baseV + (size_t)(l * 8 + rg) * SEQ + kv1 + cg * 8, &Vs[nb][l * 512]);
            }
        }
        const int kv0 = kt * 64;
        const int masked = (kt >= 2 * qb);

        // K fragments shared by both q-groups: a-frag of S^T = K[kv][d]
        short8 kf[4][2];
        #pragma unroll
        for (int g = 0; g < 4; g++) {
            kf[g][0] = *(const short8*)&Ks[cur][(g * 16 + lane15) * 64 + ((quad ^ sw) * 8)];
            kf[g][1] = *(const short8*)&Ks[cur][(g * 16 + lane15) * 64 + (((quad + 4) ^ sw) * 8)];
        }

        #pragma unroll
        for (int mm = 0; mm < 2; mm++) {
            const int qrow = q0 + wave * 32 + mm * 16 + lane15;
            const int rowOff = psBase + (mm * 16 + lane15) * 64;
            #pragma unroll
            for (int g = 0; g < 4; g++) {
                // z = S^T[kv = kv0+g*16+quad*4+r][q = qrow]
                floatx4 z = {0.f, 0.f, 0.f, 0.f};
                z = __builtin_amdgcn_mfma_f32_16x16x32_bf16(kf[g][0], qf[mm][0], z, 0, 0, 0);
                z = __builtin_amdgcn_mfma_f32_16x16x32_bf16(kf[g][1], qf[mm][1], z, 0, 0, 0);
                if (masked) {
                    #pragma unroll
                    for (int r = 0; r < 4; r++) {
                        const int col = kv0 + g * 16 + quad * 4 + r;
                        z[r] = (col <= qrow) ? z[r] : -1e30f;
                    }
                }
                // p = 2^z (raw v_exp_f32: 2^-1e30 -> 0 for masked lanes)
                const float p0 = fast_exp2(z[0]), p1 = fast_exp2(z[1]);
                const float p2 = fast_exp2(z[2]), p3 = fast_exp2(z[3]);
                unsigned int lo, hi;
                asm("v_cvt_pk_bf16_f32 %0, %1, %2" : "=v"(lo) : "v"(p0), "v"(p1));
                asm("v_cvt_pk_bf16_f32 %0, %1, %2" : "=v"(hi) : "v"(p2), "v"(p3));
                uint2 w; w.x = lo; w.y = hi;
                // logical 8B-chunk c = g*4+quad; physical = c ^ (row&15)
                *(uint2*)&Ps[rowOff + (((g * 4 + quad) ^ lane15) * 4)] = w;
            }
        }
        // Ps wave-private: lgkmcnt auto-wait orders write->read, no barrier

        #pragma unroll
        for (int kk = 0; kk < 2; kk++) {
            #pragma unroll
            for (int mm = 0; mm < 2; mm++) {
                // A-frag: logical chunks c0 = kk*8+quad*2, c0+1; swizzled apart
                const int rowOff = psBase + (mm * 16 + lane15) * 64;
                const int c0 = kk * 8 + quad * 2;
                short8 a;
                ((uint2*)&a)[0] = *(const uint2*)&Ps[rowOff + (((c0    ) ^ lane15) * 4)];
                ((uint2*)&a)[1] = *(const uint2*)&Ps[rowOff + (((c0 + 1) ^ lane15) * 4)];
                #pragma unroll
                for (int jn = 0; jn < 4; jn++) {
                    short8 bb = *(const short8*)&Vs[cur][(jn * 16 + lane15) * 64 + (((kk * 4 + quad) ^ sw) * 8)];
                    o[mm][jn] = __builtin_amdgcn_mfma_f32_16x16x32_bf16(a, bb, o[mm][jn], 0, 0, 0);
                }
                o[mm][4] = __builtin_amdgcn_mfma_f32_16x16x32_bf16(a, kOnes, o[mm][4], 0, 0, 0);
            }
        }
    }

    // epilogue: Y = O / l
    #pragma unroll
    for (int mm = 0; mm < 2; mm++)
        #pragma unroll
        for (int r = 0; r < 4; r++) {
            const int qrow = q0 + wave * 32 + mm * 16 + quad * 4 + r;
            const float rinv = 1.0f / fmaxf(o[mm][4][r], 1e-30f);
            #pragma unroll
            for (int jn = 0; jn < 4; jn++)
                QY[baseR + (size_t)qrow * CH + jn * 16 + lane15] = f2b(o[mm][jn][r] * rinv);
        }
}

extern "C" void kernel_launch(void* const* d_in, const int* in_sizes, int n_in,
                              void* d_out, int out_size, void* d_ws, size_t ws_size,
                              hipStream_t stream) {
    const void* x  = d_in[0];
    const void* Wk = d_in[1];
    const void* bk = d_in[2];
    const void* Wq = d_in[3];
    const void* bq = d_in[4];
    const void* Wv = d_in[5];
    const void* bv = d_in[6];
    const void* Wo = d_in[7];
    const void* bo = d_in[8];

    ushort_t* ws    = (ushort_t*)d_ws;
    int*      flag  = (int*)d_ws;
    ushort_t* biasC = ws + 2048;                    // 4x1024: q,k,v,o (contiguous)
    ushort_t* WqkvT = ws + 32768;                   // 3x1M contiguous: q,k,v
    ushort_t* WoT   = WqkvT + 3u * (1u << 20);
    ushort_t* xb    = ws + 4227072;                 // 8M elems bf16
    ushort_t* Qb    = ws + 12615680;                // 8M elems (becomes Y)
    ushort_t* Kb    = (ushort_t*)d_out;             // d_out scratch until final GEMM
    ushort_t* VtB   = Kb + (size_t)MROWS * CH;

    // one fused prep kernel: detect + weights + bias + x (x skipped if bf16)
    prep_all<<<dim3(8208), 256, 0, stream>>>(x, Wq, Wk, Wv, Wo, bq, bk, bv, bo,
                                             WqkvT, WoT, biasC, xb, flag);

    // scale = (1/sqrt(64)) * log2(e), folded into Q so attention uses exp2
    gemm_qkv8<<<dim3(768), 512, 0, stream>>>(x, xb, flag, WqkvT, biasC, Qb, Kb, VtB,
                                             0.1803368801f);

    attn_fwd<<<dim3(1024), 256, 0, stream>>>(Qb, Kb, VtB);

    gemm_bt8<<<dim3(256), 512, 0, stream>>>(Qb, WoT, biasC + 3072, d_out, flag);
}